// Round 2
// baseline (846.781 us; speedup 1.0000x reference)
//
#include <hip/hip_runtime.h>
#include <hip/hip_bf16.h>

// ---------------------------------------------------------------------------
// MeshEstimator (SMPL-like) forward.  B=256, R=6890, 24 joints, 207 pose dims.
// R1 -> R2: k4 restructured for occupancy (BT 32->8, grid 243->891 blocks,
// LDS 62KB->16KB, weights in registers, single barrier). k_order ballot-based.
// ---------------------------------------------------------------------------

#define NB 256
#define NR 6890
#define NJ 24
#define BT 8    // batches per vertex-kernel block

// ---- output offsets (floats) ----
#define OFF_BETAS 0
#define OFF_POSE  2560
#define OFF_RSH   20992
#define OFF_RA    21760
#define OFF_VERTS 23296
#define OFF_VRED  5314816
#define OFF_NEWJ  5322496
#define OFF_VOFF  5340928

// ---- workspace offsets (floats) ----
#define WS_RS    0         // Rs: 256*24*9 = 55296
#define WS_PF    55296     // pose_feat: 256*207 = 52992
#define WS_BETA  108288    // 2560
#define WS_RSH   110848    // 768
#define WS_GI    111616    // 256 ints
#define WS_JT    111872    // 2*24*3 = 144
#define WS_JS    112016    // 2*10*24*3 = 1440
#define WS_A     113456    // 256*24*12 = 73728
#define WS_J0S   187184    // 768
#define WS_ORD   187952    // 256 ints
#define WS_CNT   188208    // 2 ints

__constant__ int PAR_c[24] = {0,0,0,0,1,2,3,4,5,6,7,8,9,9,9,12,13,14,16,17,18,19,20,21};
__constant__ int VL_c[10]  = {1325,336,1032,4515,1374,4848,1739,5209,1960,5423};
__constant__ int SY_c[10]  = {3,15,4,5,7,8,18,19,20,21};

__constant__ float BLO[72] = {
  -0.5933865286111969f, -6.283185307179586f, -1.215762200416361f,
  -1.5793940868065197f, -0.5881754611f, -0.5323249722f,
  -1.5793940868065197f, -0.5689768556f, -0.6736965222f,
  -1.0471975511965976f, -0.08726646259971647f, -0.08726646259971647f,
  -0.02268926111f, -0.01f, -0.01f,
  -0.02268926111f, -0.01f, -0.01f,
  -1.0471975511965976f, -0.08726646259971647f, -0.08726646259971647f,
  -0.5235987755982988f, -0.5235987755982988f, -0.5235987755982988f,
  -0.5235987755982988f, -0.5235987755982988f, -0.5235987755982988f,
  -1.0471975511965976f, -0.08726646259971647f, -0.08726646259971647f,
  -0.01f, -0.01f, -0.01f, -0.01f, -0.01f, -0.01f,
  -1.0471975511965976f, -0.08726646259971647f, -0.08726646259971647f,
  (float)(-1.551596394/3.0), (float)(-2.455676183/3.0), (float)(-1.570795/3.0),
  (float)(-1.551596394/3.0), (float)(-0.7627082389/3.0), (float)(-2.188641033/3.0),
  -1.0471975511965976f, -0.08726646259971647f, -0.08726646259971647f,
  (float)(-1.551596394*2.0/3.0), (float)(-2.455676183*2.0/3.0), (float)(-1.570795*2.0/3.0),
  (float)(-1.551596394*2.0/3.0), (float)(-0.7627082389*2.0/3.0), (float)(-2.188641033*2.0/3.0),
  -0.01f, -2.570867817f, -0.01f, -0.01f, -0.04799651389f, -0.01f,
  -0.5235987755982988f, -0.5235987755982988f, -0.5235987755982988f,
  -0.5235987755982988f, -0.5235987755982988f, -0.5235987755982988f,
  -0.01f, -0.01f, -0.01f, -0.01f, -0.01f, -0.01f
};
__constant__ float BHI[72] = {
  0.5933865286111969f, 6.283185307179586f, 1.215762200416361f,
  0.3097956806f, 0.5689768556f, 0.6736965222f,
  0.3097956806f, 0.5881754611f, 0.5323249722f,
  1.0471975511965976f, 0.08726646259971647f, 0.08726646259971647f,
  2.441713561f, 0.01f, 0.01f,
  2.441713561f, 0.01f, 0.01f,
  1.0471975511965976f, 0.08726646259971647f, 0.08726646259971647f,
  0.5235987755982988f, 0.5235987755982988f, 0.5235987755982988f,
  0.5235987755982988f, 0.5235987755982988f, 0.5235987755982988f,
  1.0471975511965976f, 0.08726646259971647f, 0.08726646259971647f,
  0.01f, 0.01f, 0.01f, 0.01f, 0.01f, 0.01f,
  1.0471975511965976f, 0.08726646259971647f, 0.08726646259971647f,
  (float)(2.206094311/3.0), (float)(0.7627082389/3.0), (float)(2.188641033/3.0),
  (float)(2.206094311/3.0), (float)(2.455676183/3.0), (float)(1.570795/3.0),
  1.0471975511965976f, 0.08726646259971647f, 0.08726646259971647f,
  (float)(2.206094311*2.0/3.0), (float)(0.7627082389*2.0/3.0), (float)(2.188641033*2.0/3.0),
  (float)(2.206094311*2.0/3.0), (float)(2.455676183*2.0/3.0), (float)(1.570795*2.0/3.0),
  0.01f, 0.04799651389f, 0.01f, 0.01f, 2.570867817f, 0.01f,
  0.5235987755982988f, 0.5235987755982988f, 0.5235987755982988f,
  0.5235987755982988f, 0.5235987755982988f, 0.5235987755982988f,
  0.01f, 0.01f, 0.01f, 0.01f, 0.01f, 0.01f
};

// ---------------------------------------------------------------------------
// K1: per-batch pose clamp, Rodrigues, betas, root outputs, gender index
// ---------------------------------------------------------------------------
__global__ void k1_pose(const float* __restrict__ x, const float* __restrict__ gen,
                        float* __restrict__ out, float* __restrict__ W)
{
  const int b = blockIdx.x, tid = threadIdx.x;
  const float* xb = x + b * 88;
  if (tid < 24) {
    const int j = tid;
    float t[3];
    if (j == 0) {
      t[0] = atan2f(xb[16], xb[13]);
      t[1] = atan2f(xb[17], xb[14]);
      t[2] = atan2f(xb[18], xb[15]);
    } else {
      t[0] = xb[19 + (j - 1) * 3 + 0];
      t[1] = xb[19 + (j - 1) * 3 + 1];
      t[2] = xb[19 + (j - 1) * 3 + 2];
    }
#pragma unroll
    for (int c = 0; c < 3; c++) {
      const int pi = j * 3 + c;
      const float lo = 2.f * BLO[pi], hi = 2.f * BHI[pi];
      const float mean = 0.5f * (lo + hi);
      const float scale = 2.f / fabsf(lo - hi);
      const float v = tanhf((t[c] - mean) * scale) / scale + mean;
      t[c] = v;
      out[OFF_POSE + b * 72 + pi] = v;
    }
    const float a0 = t[0] + 1e-8f, a1 = t[1] + 1e-8f, a2 = t[2] + 1e-8f;
    const float ang = sqrtf(a0 * a0 + a1 * a1 + a2 * a2);
    const float half = 0.5f * ang;
    const float sh = sinf(half), ch = cosf(half);
    const float inv = sh / ang;
    float qw = ch, qx = t[0] * inv, qy = t[1] * inv, qz = t[2] * inv;
    const float nn = sqrtf(qw * qw + qx * qx + qy * qy + qz * qz);
    qw /= nn; qx /= nn; qy /= nn; qz /= nn;
    float R[9];
    R[0] = 1.f - 2.f * (qy * qy + qz * qz); R[1] = 2.f * (qx * qy - qw * qz); R[2] = 2.f * (qx * qz + qw * qy);
    R[3] = 2.f * (qx * qy + qw * qz); R[4] = 1.f - 2.f * (qx * qx + qz * qz); R[5] = 2.f * (qy * qz - qw * qx);
    R[6] = 2.f * (qx * qz - qw * qy); R[7] = 2.f * (qy * qz + qw * qx); R[8] = 1.f - 2.f * (qx * qx + qy * qy);
    float* rsw = W + WS_RS + (size_t)(b * 24 + j) * 9;
#pragma unroll
    for (int e = 0; e < 9; e++) rsw[e] = R[e];
    if (j >= 1) {
      float* pfw = W + WS_PF + (size_t)b * 207 + (j - 1) * 9;
#pragma unroll
      for (int e = 0; e < 9; e++)
        pfw[e] = R[e] - ((e == 0 || e == 4 || e == 8) ? 1.f : 0.f);
    }
  } else if (tid < 34) {
    const int k = tid - 24;
    const float v = tanhf(xb[k] / 3.0f) * 3.0f;
    out[OFF_BETAS + b * 10 + k] = v;
    W[WS_BETA + b * 10 + k] = v;
  } else if (tid == 34) {
    const float r0 = xb[10] + (0.6f - 0.286f);
    const float r1 = xb[11] + (1.2f - 0.286f);
    const float r2 = xb[12] + 0.1f;
    out[OFF_RSH + b * 3 + 0] = r0; out[OFF_RSH + b * 3 + 1] = r1; out[OFF_RSH + b * 3 + 2] = r2;
    W[WS_RSH + b * 3 + 0] = r0; W[WS_RSH + b * 3 + 1] = r1; W[WS_RSH + b * 3 + 2] = r2;
#pragma unroll
    for (int k2 = 0; k2 < 6; k2++) out[OFF_RA + b * 6 + k2] = xb[13 + k2];
  } else if (tid == 35) {
    ((int*)(W + WS_GI))[b] = (gen[b * 2 + 1] > gen[b * 2 + 0]) ? 1 : 0;
  }
}

// ---------------------------------------------------------------------------
// K2: per-gender joint regressor decomposition (512 threads for latency hiding)
// ---------------------------------------------------------------------------
__global__ void k2_jreg(const float* __restrict__ vtemp, const float* __restrict__ sdirs,
                        const float* __restrict__ jreg, float* __restrict__ W)
{
  const int g = blockIdx.x / 24, j = blockIdx.x % 24;
  const float* vtg = vtemp + (size_t)g * NR * 3;
  const float* sdg = sdirs + (size_t)g * 10 * NR * 3;
  const float* jrg = jreg + (size_t)g * NR * 24;
  float acc[33];
#pragma unroll
  for (int e = 0; e < 33; e++) acc[e] = 0.f;
  for (int r = threadIdx.x; r < NR; r += 512) {
    const float w = jrg[r * 24 + j];
    acc[0] += vtg[r * 3 + 0] * w;
    acc[1] += vtg[r * 3 + 1] * w;
    acc[2] += vtg[r * 3 + 2] * w;
#pragma unroll
    for (int k = 0; k < 10; k++) {
      const float* s = sdg + ((size_t)k * NR + r) * 3;
      acc[3 + k * 3 + 0] += s[0] * w;
      acc[3 + k * 3 + 1] += s[1] * w;
      acc[3 + k * 3 + 2] += s[2] * w;
    }
  }
  __shared__ float red[8][33];
  const int lane = threadIdx.x & 63, wv = threadIdx.x >> 6;
#pragma unroll
  for (int e = 0; e < 33; e++) {
    float v = acc[e];
    v += __shfl_down(v, 32); v += __shfl_down(v, 16); v += __shfl_down(v, 8);
    v += __shfl_down(v, 4);  v += __shfl_down(v, 2);  v += __shfl_down(v, 1);
    if (lane == 0) red[wv][e] = v;
  }
  __syncthreads();
  if (threadIdx.x < 33) {
    const int e = threadIdx.x;
    float v = 0.f;
#pragma unroll
    for (int w2 = 0; w2 < 8; w2++) v += red[w2][e];
    if (e < 3) W[WS_JT + (g * 24 + j) * 3 + e] = v;
    else {
      const int k = (e - 3) / 3, d = (e - 3) % 3;
      W[WS_JS + ((g * 10 + k) * 24 + j) * 3 + d] = v;
    }
  }
}

// ---------------------------------------------------------------------------
// K_order: ballot-based stable compaction of batches by gender (1 block, 256 thr)
// ---------------------------------------------------------------------------
__global__ void k_order(float* __restrict__ W)
{
  const int tid = threadIdx.x;              // == batch index
  const int* gi = (const int*)(W + WS_GI);
  int* ord = (int*)(W + WS_ORD);
  int* cnt = (int*)(W + WS_CNT);
  const int g = gi[tid];
  const int lane = tid & 63, wv = tid >> 6;
  const unsigned long long b0 = __ballot(g == 0);
  __shared__ int c0[4];
  if (lane == 0) c0[wv] = __popcll(b0);
  __syncthreads();
  const int t0 = c0[0] + c0[1] + c0[2] + c0[3];
  int off0 = 0, off1 = t0;
  for (int w = 0; w < wv; w++) { off0 += c0[w]; off1 += 64 - c0[w]; }
  const unsigned long long ltm = (1ull << lane) - 1ull;
  const int r0 = __popcll(b0 & ltm);
  const int r1 = lane - r0;
  if (g == 0) ord[off0 + r0] = tid;
  else        ord[off1 + r1] = tid;
  if (tid == 0) { cnt[0] = t0; cnt[1] = NB - t0; }
}

// ---------------------------------------------------------------------------
// K3: per-batch: J from decomposition, kinematic chain, new_J out, A to ws
// ---------------------------------------------------------------------------
__launch_bounds__(128)
__global__ void k3_chain(float* __restrict__ out, float* __restrict__ W)
{
  const int b = blockIdx.x, tid = threadIdx.x;
  __shared__ float J[72];
  __shared__ float G[24][12];
  __shared__ float j0s[3];
  const int gi = ((const int*)(W + WS_GI))[b];
  if (tid < 72) {
    const int j = tid / 3, d = tid % 3;
    float v = W[WS_JT + (gi * 24 + j) * 3 + d];
    const float* bet = W + WS_BETA + b * 10;
#pragma unroll
    for (int k = 0; k < 10; k++)
      v += bet[k] * W[WS_JS + ((gi * 10 + k) * 24 + j) * 3 + d];
    J[tid] = v;
  }
  __syncthreads();
  const float* Rs = W + WS_RS + (size_t)b * 216;
  if (tid < 12) {
    const int row = tid / 4, col = tid % 4;
    G[0][tid] = (col < 3) ? Rs[row * 3 + col] : J[row];
  }
  __syncthreads();
  for (int i = 1; i < 24; i++) {
    const int p = PAR_c[i];
    if (tid < 12) {
      const int row = tid / 4, col = tid % 4;
      const float* Ri = Rs + i * 9;
      const float g0 = G[p][row * 4 + 0], g1 = G[p][row * 4 + 1], g2 = G[p][row * 4 + 2];
      float v;
      if (col < 3) {
        v = g0 * Ri[col] + g1 * Ri[3 + col] + g2 * Ri[6 + col];
      } else {
        const float t0 = J[i * 3 + 0] - J[p * 3 + 0];
        const float t1 = J[i * 3 + 1] - J[p * 3 + 1];
        const float t2 = J[i * 3 + 2] - J[p * 3 + 2];
        v = g0 * t0 + g1 * t1 + g2 * t2 + G[p][row * 4 + 3];
      }
      G[i][tid] = v;
    }
    __syncthreads();
  }
  if (tid < 3) {
    const float v = W[WS_RSH + b * 3 + tid] - J[tid];
    j0s[tid] = v;
    W[WS_J0S + b * 3 + tid] = v;
  }
  __syncthreads();
  if (tid < 72) {
    const int j = tid / 3, d = tid % 3;
    out[OFF_NEWJ + (size_t)b * 72 + tid] = G[j][d * 4 + 3] + j0s[d];
  }
  for (int e = tid; e < 288; e += 128) {
    const int j = e / 12, rc = e % 12, row = rc / 4, col = rc % 4;
    float v = G[j][rc];
    if (col == 3)
      v -= G[j][row * 4 + 0] * J[j * 3 + 0] + G[j][row * 4 + 1] * J[j * 3 + 1] + G[j][row * 4 + 2] * J[j * 3 + 2];
    W[WS_A + (size_t)b * 288 + e] = v;
  }
}

// ---------------------------------------------------------------------------
// K4: vertices. Block = 256 verts x BT=8 batches (one gender). 891 blocks.
// Single __syncthreads: stage pf/bet/j0s/bidx/A first, then phase1+phase2.
// ---------------------------------------------------------------------------
__launch_bounds__(256, 4)
__global__ void k4_verts(const float* __restrict__ vtemp, const float* __restrict__ sdirs,
                         const float* __restrict__ pdirs, const float* __restrict__ wts,
                         float* __restrict__ out, const float* __restrict__ W)
{
  __shared__ __align__(16) float s_pf[BT][208];
  __shared__ float s_bet[BT][10];
  __shared__ float s_j0s[BT][3];
  __shared__ __align__(16) float s_A[BT][288];
  __shared__ int s_bidx[BT];

  const int tid = threadIdx.x;
  const int* cnt = (const int*)(W + WS_CNT);
  const int B0 = cnt[0];
  const int T0 = (B0 + BT - 1) / BT;
  const int bt = blockIdx.y;
  int g, start, n;
  if (bt < T0) { g = 0; start = bt * BT; n = B0 - start; }
  else { g = 1; start = B0 + (bt - T0) * BT; n = NB - start; }
  if (n > BT) n = BT;
  if (n <= 0) return;   // uniform exit

  const int* ord = (const int*)(W + WS_ORD);
  if (tid < BT) s_bidx[tid] = (tid < n) ? ord[start + tid] : ord[start];

  // ---- staging (single barrier after all of it) ----
  for (int e = tid; e < BT * 208; e += 256) {
    const int i = e / 208, p = e - i * 208;
    const int b = ord[start + (i < n ? i : 0)];
    s_pf[i][p] = (p < 207) ? W[WS_PF + (size_t)b * 207 + p] : 0.f;
  }
  for (int e = tid; e < BT * 10; e += 256) {
    const int i = e / 10, k = e - i * 10;
    const int b = ord[start + (i < n ? i : 0)];
    s_bet[i][k] = W[WS_BETA + b * 10 + k];
  }
  if (tid < BT * 3) {
    const int i = tid / 3, d = tid - i * 3;
    const int b = ord[start + (i < n ? i : 0)];
    s_j0s[i][d] = W[WS_J0S + b * 3 + d];
  }
  for (int e = tid; e < BT * 288; e += 256) {
    const int i = e / 288, rem = e - i * 288;
    const int b = ord[start + (i < n ? i : 0)];
    s_A[i][rem] = W[WS_A + (size_t)b * 288 + rem];
  }
  __syncthreads();

  const int r = blockIdx.x * 256 + tid;
  const bool active = (r < NR);
  float acc[BT][3];

  if (active) {
    const float* vt3 = vtemp + ((size_t)g * NR + r) * 3;
    const float vt0 = vt3[0], vt1 = vt3[1], vt2 = vt3[2];
    float sdr[10][3];
#pragma unroll
    for (int k = 0; k < 10; k++) {
      const float* s = sdirs + ((size_t)g * 10 * NR + (size_t)k * NR + r) * 3;
      sdr[k][0] = s[0]; sdr[k][1] = s[1]; sdr[k][2] = s[2];
    }
#pragma unroll
    for (int i = 0; i < BT; i++) {
      float a0 = vt0, a1 = vt1, a2 = vt2;
#pragma unroll
      for (int k = 0; k < 10; k++) {
        const float bk = s_bet[i][k];
        a0 += bk * sdr[k][0]; a1 += bk * sdr[k][1]; a2 += bk * sdr[k][2];
      }
      acc[i][0] = a0; acc[i][1] = a1; acc[i][2] = a2;
    }
    const float* pdr = pdirs + ((size_t)g * NR + r) * 621;
    for (int p0 = 0; p0 < 200; p0 += 8) {
      float pdv0[8], pdv1[8], pdv2[8];
#pragma unroll
      for (int t = 0; t < 8; t++) {
        pdv0[t] = pdr[p0 + t];
        pdv1[t] = pdr[207 + p0 + t];
        pdv2[t] = pdr[414 + p0 + t];
      }
#pragma unroll
      for (int i = 0; i < BT; i++) {
        const float4 f0 = *(const float4*)&s_pf[i][p0];
        const float4 f1 = *(const float4*)&s_pf[i][p0 + 4];
        const float pfv[8] = { f0.x, f0.y, f0.z, f0.w, f1.x, f1.y, f1.z, f1.w };
        float a0 = acc[i][0], a1 = acc[i][1], a2 = acc[i][2];
#pragma unroll
        for (int t = 0; t < 8; t++) {
          a0 += pfv[t] * pdv0[t];
          a1 += pfv[t] * pdv1[t];
          a2 += pfv[t] * pdv2[t];
        }
        acc[i][0] = a0; acc[i][1] = a1; acc[i][2] = a2;
      }
    }
    { // tail p = 200..206
      float pdv0[7], pdv1[7], pdv2[7];
#pragma unroll
      for (int t = 0; t < 7; t++) {
        pdv0[t] = pdr[200 + t];
        pdv1[t] = pdr[407 + t];
        pdv2[t] = pdr[614 + t];
      }
#pragma unroll
      for (int i = 0; i < BT; i++) {
        float a0 = acc[i][0], a1 = acc[i][1], a2 = acc[i][2];
#pragma unroll
        for (int t = 0; t < 7; t++) {
          const float pv = s_pf[i][200 + t];
          a0 += pv * pdv0[t]; a1 += pv * pdv1[t]; a2 += pv * pdv2[t];
        }
        acc[i][0] = a0; acc[i][1] = a1; acc[i][2] = a2;
      }
    }

    // ---- phase 2: LBS skinning, weights in registers, A broadcast from LDS ----
    float w[24];
    const float* wr = wts + ((size_t)g * NR + r) * 24;
#pragma unroll
    for (int j = 0; j < 24; j += 4) {
      const float4 wv = *(const float4*)&wr[j];
      w[j] = wv.x; w[j + 1] = wv.y; w[j + 2] = wv.z; w[j + 3] = wv.w;
    }
#pragma unroll
    for (int i = 0; i < BT; i++) {
      float T[12];
#pragma unroll
      for (int e = 0; e < 12; e++) T[e] = 0.f;
#pragma unroll
      for (int j = 0; j < 24; j++) {
        const float wj = w[j];
        const float4 a0 = *(const float4*)&s_A[i][j * 12];
        const float4 a1 = *(const float4*)&s_A[i][j * 12 + 4];
        const float4 a2 = *(const float4*)&s_A[i][j * 12 + 8];
        T[0] += wj * a0.x; T[1] += wj * a0.y; T[2]  += wj * a0.z; T[3]  += wj * a0.w;
        T[4] += wj * a1.x; T[5] += wj * a1.y; T[6]  += wj * a1.z; T[7]  += wj * a1.w;
        T[8] += wj * a2.x; T[9] += wj * a2.y; T[10] += wj * a2.z; T[11] += wj * a2.w;
      }
      if (i < n) {
        const float vx = acc[i][0], vy = acc[i][1], vz = acc[i][2];
        const float o0 = T[0] * vx + T[1] * vy + T[2]  * vz + T[3]  + s_j0s[i][0];
        const float o1 = T[4] * vx + T[5] * vy + T[6]  * vz + T[7]  + s_j0s[i][1];
        const float o2 = T[8] * vx + T[9] * vy + T[10] * vz + T[11] + s_j0s[i][2];
        float* op = out + OFF_VERTS + ((size_t)s_bidx[i] * NR + r) * 3;
        op[0] = o0; op[1] = o1; op[2] = o2;
      }
    }
  }
}

// ---------------------------------------------------------------------------
// K5: gather verts_red and verts_offset
// ---------------------------------------------------------------------------
__global__ void k5_gather(float* __restrict__ out)
{
  const int idx = blockIdx.x * 256 + threadIdx.x;
  if (idx >= NB * 10 * 3) return;
  const int b = idx / 30, rem = idx % 30, i = rem / 3, d = rem % 3;
  const float v = out[OFF_VERTS + ((size_t)b * NR + VL_c[i]) * 3 + d];
  out[OFF_VRED + idx] = v;
  out[OFF_VOFF + idx] = v - out[OFF_NEWJ + (size_t)b * 72 + SY_c[i] * 3 + d];
}

// ---------------------------------------------------------------------------
extern "C" void kernel_launch(void* const* d_in, const int* in_sizes, int n_in,
                              void* d_out, int out_size, void* d_ws, size_t ws_size,
                              hipStream_t stream)
{
  const float* x   = (const float*)d_in[0];
  const float* gen = (const float*)d_in[1];
  const float* vt  = (const float*)d_in[2];
  const float* sd  = (const float*)d_in[3];
  const float* jr  = (const float*)d_in[4];
  const float* pd  = (const float*)d_in[5];
  const float* wt  = (const float*)d_in[6];
  float* out = (float*)d_out;
  float* W   = (float*)d_ws;

  k1_pose<<<NB, 64, 0, stream>>>(x, gen, out, W);
  k2_jreg<<<48, 512, 0, stream>>>(vt, sd, jr, W);
  k_order<<<1, 256, 0, stream>>>(W);
  k3_chain<<<NB, 128, 0, stream>>>(out, W);
  dim3 g4(27, 33);   // 891 blocks: ~3.5 blocks/CU
  k4_verts<<<g4, 256, 0, stream>>>(vt, sd, pd, wt, out, W);
  k5_gather<<<30, 256, 0, stream>>>(out);
}

// Round 3
// 147.329 us; speedup vs baseline: 5.7475x; 5.7475x over previous
//
#include <hip/hip_runtime.h>
#include <hip/hip_bf16.h>

// ---------------------------------------------------------------------------
// MeshEstimator (SMPL-like) forward.  B=256, R=6890, 24 joints, 207 pose dims.
// R2 -> R3: posedirs contraction restructured as bf16 MFMA GEMM (k4a) so PD
// is streamed ONCE, coalesced (R2: 1.88GB fetch; ideal 68MB). k4b does
// v_shaped + LBS only. VP staged in the out-verts region (read then overwrite).
// ---------------------------------------------------------------------------

#define NB 256
#define NR 6890
#define NJ 24
#define BT 16       // batches per k4b block
#define RD3 (NR*3)  // 20670
#define KPD 207

// ---- output offsets (floats) ----
#define OFF_BETAS 0
#define OFF_POSE  2560
#define OFF_RSH   20992
#define OFF_RA    21760
#define OFF_VERTS 23296
#define OFF_VRED  5314816
#define OFF_NEWJ  5322496
#define OFF_VOFF  5340928

// ---- workspace offsets (floats) ----
#define WS_RS    0         // Rs: 256*24*9 = 55296
#define WS_PF    55296     // pose_feat: 256*207 = 52992
#define WS_BETA  108288    // 2560
#define WS_RSH   110848    // 768
#define WS_GI    111616    // 256 ints
#define WS_JT    111872    // 2*24*3 = 144
#define WS_JS    112016    // 2*10*24*3 = 1440
#define WS_A     113456    // 256*24*12 = 73728
#define WS_J0S   187184    // 768
#define WS_ORD   187952    // 256 ints
#define WS_CNT   188208    // 2 ints
#define WS_PFB   188224    // bf16 A-matrix: 2*256*224 ushort = 57344 floats

typedef short v8s __attribute__((ext_vector_type(8)));
typedef float v4f __attribute__((ext_vector_type(4)));

__constant__ int PAR_c[24] = {0,0,0,0,1,2,3,4,5,6,7,8,9,9,9,12,13,14,16,17,18,19,20,21};
__constant__ int VL_c[10]  = {1325,336,1032,4515,1374,4848,1739,5209,1960,5423};
__constant__ int SY_c[10]  = {3,15,4,5,7,8,18,19,20,21};

__constant__ float BLO[72] = {
  -0.5933865286111969f, -6.283185307179586f, -1.215762200416361f,
  -1.5793940868065197f, -0.5881754611f, -0.5323249722f,
  -1.5793940868065197f, -0.5689768556f, -0.6736965222f,
  -1.0471975511965976f, -0.08726646259971647f, -0.08726646259971647f,
  -0.02268926111f, -0.01f, -0.01f,
  -0.02268926111f, -0.01f, -0.01f,
  -1.0471975511965976f, -0.08726646259971647f, -0.08726646259971647f,
  -0.5235987755982988f, -0.5235987755982988f, -0.5235987755982988f,
  -0.5235987755982988f, -0.5235987755982988f, -0.5235987755982988f,
  -1.0471975511965976f, -0.08726646259971647f, -0.08726646259971647f,
  -0.01f, -0.01f, -0.01f, -0.01f, -0.01f, -0.01f,
  -1.0471975511965976f, -0.08726646259971647f, -0.08726646259971647f,
  (float)(-1.551596394/3.0), (float)(-2.455676183/3.0), (float)(-1.570795/3.0),
  (float)(-1.551596394/3.0), (float)(-0.7627082389/3.0), (float)(-2.188641033/3.0),
  -1.0471975511965976f, -0.08726646259971647f, -0.08726646259971647f,
  (float)(-1.551596394*2.0/3.0), (float)(-2.455676183*2.0/3.0), (float)(-1.570795*2.0/3.0),
  (float)(-1.551596394*2.0/3.0), (float)(-0.7627082389*2.0/3.0), (float)(-2.188641033*2.0/3.0),
  -0.01f, -2.570867817f, -0.01f, -0.01f, -0.04799651389f, -0.01f,
  -0.5235987755982988f, -0.5235987755982988f, -0.5235987755982988f,
  -0.5235987755982988f, -0.5235987755982988f, -0.5235987755982988f,
  -0.01f, -0.01f, -0.01f, -0.01f, -0.01f, -0.01f
};
__constant__ float BHI[72] = {
  0.5933865286111969f, 6.283185307179586f, 1.215762200416361f,
  0.3097956806f, 0.5689768556f, 0.6736965222f,
  0.3097956806f, 0.5881754611f, 0.5323249722f,
  1.0471975511965976f, 0.08726646259971647f, 0.08726646259971647f,
  2.441713561f, 0.01f, 0.01f,
  2.441713561f, 0.01f, 0.01f,
  1.0471975511965976f, 0.08726646259971647f, 0.08726646259971647f,
  0.5235987755982988f, 0.5235987755982988f, 0.5235987755982988f,
  0.5235987755982988f, 0.5235987755982988f, 0.5235987755982988f,
  1.0471975511965976f, 0.08726646259971647f, 0.08726646259971647f,
  0.01f, 0.01f, 0.01f, 0.01f, 0.01f, 0.01f,
  1.0471975511965976f, 0.08726646259971647f, 0.08726646259971647f,
  (float)(2.206094311/3.0), (float)(0.7627082389/3.0), (float)(2.188641033/3.0),
  (float)(2.206094311/3.0), (float)(2.455676183/3.0), (float)(1.570795/3.0),
  1.0471975511965976f, 0.08726646259971647f, 0.08726646259971647f,
  (float)(2.206094311*2.0/3.0), (float)(0.7627082389*2.0/3.0), (float)(2.188641033*2.0/3.0),
  (float)(2.206094311*2.0/3.0), (float)(2.455676183*2.0/3.0), (float)(1.570795*2.0/3.0),
  0.01f, 0.04799651389f, 0.01f, 0.01f, 2.570867817f, 0.01f,
  0.5235987755982988f, 0.5235987755982988f, 0.5235987755982988f,
  0.5235987755982988f, 0.5235987755982988f, 0.5235987755982988f,
  0.01f, 0.01f, 0.01f, 0.01f, 0.01f, 0.01f
};

__device__ __forceinline__ unsigned short f2bf(float f) {
  union { float f; unsigned u; } c; c.f = f;
  const unsigned u = c.u + 0x7FFFu + ((c.u >> 16) & 1u);   // RNE
  return (unsigned short)(u >> 16);
}

// ---------------------------------------------------------------------------
// K1: per-batch pose clamp, Rodrigues, betas, root outputs, gender index
// ---------------------------------------------------------------------------
__global__ void k1_pose(const float* __restrict__ x, const float* __restrict__ gen,
                        float* __restrict__ out, float* __restrict__ W)
{
  const int b = blockIdx.x, tid = threadIdx.x;
  const float* xb = x + b * 88;
  if (tid < 24) {
    const int j = tid;
    float t[3];
    if (j == 0) {
      t[0] = atan2f(xb[16], xb[13]);
      t[1] = atan2f(xb[17], xb[14]);
      t[2] = atan2f(xb[18], xb[15]);
    } else {
      t[0] = xb[19 + (j - 1) * 3 + 0];
      t[1] = xb[19 + (j - 1) * 3 + 1];
      t[2] = xb[19 + (j - 1) * 3 + 2];
    }
#pragma unroll
    for (int c = 0; c < 3; c++) {
      const int pi = j * 3 + c;
      const float lo = 2.f * BLO[pi], hi = 2.f * BHI[pi];
      const float mean = 0.5f * (lo + hi);
      const float scale = 2.f / fabsf(lo - hi);
      const float v = tanhf((t[c] - mean) * scale) / scale + mean;
      t[c] = v;
      out[OFF_POSE + b * 72 + pi] = v;
    }
    const float a0 = t[0] + 1e-8f, a1 = t[1] + 1e-8f, a2 = t[2] + 1e-8f;
    const float ang = sqrtf(a0 * a0 + a1 * a1 + a2 * a2);
    const float half = 0.5f * ang;
    const float sh = sinf(half), ch = cosf(half);
    const float inv = sh / ang;
    float qw = ch, qx = t[0] * inv, qy = t[1] * inv, qz = t[2] * inv;
    const float nn = sqrtf(qw * qw + qx * qx + qy * qy + qz * qz);
    qw /= nn; qx /= nn; qy /= nn; qz /= nn;
    float R[9];
    R[0] = 1.f - 2.f * (qy * qy + qz * qz); R[1] = 2.f * (qx * qy - qw * qz); R[2] = 2.f * (qx * qz + qw * qy);
    R[3] = 2.f * (qx * qy + qw * qz); R[4] = 1.f - 2.f * (qx * qx + qz * qz); R[5] = 2.f * (qy * qz - qw * qx);
    R[6] = 2.f * (qx * qz - qw * qy); R[7] = 2.f * (qy * qz + qw * qx); R[8] = 1.f - 2.f * (qx * qx + qy * qy);
    float* rsw = W + WS_RS + (size_t)(b * 24 + j) * 9;
#pragma unroll
    for (int e = 0; e < 9; e++) rsw[e] = R[e];
    if (j >= 1) {
      float* pfw = W + WS_PF + (size_t)b * 207 + (j - 1) * 9;
#pragma unroll
      for (int e = 0; e < 9; e++)
        pfw[e] = R[e] - ((e == 0 || e == 4 || e == 8) ? 1.f : 0.f);
    }
  } else if (tid < 34) {
    const int k = tid - 24;
    const float v = tanhf(xb[k] / 3.0f) * 3.0f;
    out[OFF_BETAS + b * 10 + k] = v;
    W[WS_BETA + b * 10 + k] = v;
  } else if (tid == 34) {
    const float r0 = xb[10] + (0.6f - 0.286f);
    const float r1 = xb[11] + (1.2f - 0.286f);
    const float r2 = xb[12] + 0.1f;
    out[OFF_RSH + b * 3 + 0] = r0; out[OFF_RSH + b * 3 + 1] = r1; out[OFF_RSH + b * 3 + 2] = r2;
    W[WS_RSH + b * 3 + 0] = r0; W[WS_RSH + b * 3 + 1] = r1; W[WS_RSH + b * 3 + 2] = r2;
#pragma unroll
    for (int k2 = 0; k2 < 6; k2++) out[OFF_RA + b * 6 + k2] = xb[13 + k2];
  } else if (tid == 35) {
    ((int*)(W + WS_GI))[b] = (gen[b * 2 + 1] > gen[b * 2 + 0]) ? 1 : 0;
  }
}

// ---------------------------------------------------------------------------
// K2: per-gender joint regressor decomposition
// ---------------------------------------------------------------------------
__global__ void k2_jreg(const float* __restrict__ vtemp, const float* __restrict__ sdirs,
                        const float* __restrict__ jreg, float* __restrict__ W)
{
  const int g = blockIdx.x / 24, j = blockIdx.x % 24;
  const float* vtg = vtemp + (size_t)g * NR * 3;
  const float* sdg = sdirs + (size_t)g * 10 * NR * 3;
  const float* jrg = jreg + (size_t)g * NR * 24;
  float acc[33];
#pragma unroll
  for (int e = 0; e < 33; e++) acc[e] = 0.f;
  for (int r = threadIdx.x; r < NR; r += 512) {
    const float w = jrg[r * 24 + j];
    acc[0] += vtg[r * 3 + 0] * w;
    acc[1] += vtg[r * 3 + 1] * w;
    acc[2] += vtg[r * 3 + 2] * w;
#pragma unroll
    for (int k = 0; k < 10; k++) {
      const float* s = sdg + ((size_t)k * NR + r) * 3;
      acc[3 + k * 3 + 0] += s[0] * w;
      acc[3 + k * 3 + 1] += s[1] * w;
      acc[3 + k * 3 + 2] += s[2] * w;
    }
  }
  __shared__ float red[8][33];
  const int lane = threadIdx.x & 63, wv = threadIdx.x >> 6;
#pragma unroll
  for (int e = 0; e < 33; e++) {
    float v = acc[e];
    v += __shfl_down(v, 32); v += __shfl_down(v, 16); v += __shfl_down(v, 8);
    v += __shfl_down(v, 4);  v += __shfl_down(v, 2);  v += __shfl_down(v, 1);
    if (lane == 0) red[wv][e] = v;
  }
  __syncthreads();
  if (threadIdx.x < 33) {
    const int e = threadIdx.x;
    float v = 0.f;
#pragma unroll
    for (int w2 = 0; w2 < 8; w2++) v += red[w2][e];
    if (e < 3) W[WS_JT + (g * 24 + j) * 3 + e] = v;
    else {
      const int k = (e - 3) / 3, d = (e - 3) % 3;
      W[WS_JS + ((g * 10 + k) * 24 + j) * 3 + d] = v;
    }
  }
}

// ---------------------------------------------------------------------------
// K_order: ballot-based stable compaction of batches by gender
// ---------------------------------------------------------------------------
__global__ void k_order(float* __restrict__ W)
{
  const int tid = threadIdx.x;              // == batch index
  const int* gi = (const int*)(W + WS_GI);
  int* ord = (int*)(W + WS_ORD);
  int* cnt = (int*)(W + WS_CNT);
  const int g = gi[tid];
  const int lane = tid & 63, wv = tid >> 6;
  const unsigned long long b0 = __ballot(g == 0);
  __shared__ int c0[4];
  if (lane == 0) c0[wv] = __popcll(b0);
  __syncthreads();
  const int t0 = c0[0] + c0[1] + c0[2] + c0[3];
  int off0 = 0, off1 = t0;
  for (int w = 0; w < wv; w++) { off0 += c0[w]; off1 += 64 - c0[w]; }
  const unsigned long long ltm = (1ull << lane) - 1ull;
  const int r0 = __popcll(b0 & ltm);
  const int r1 = lane - r0;
  if (g == 0) ord[off0 + r0] = tid;
  else        ord[off1 + r1] = tid;
  if (tid == 0) { cnt[0] = t0; cnt[1] = NB - t0; }
}

// ---------------------------------------------------------------------------
// K_pf: pack pose features into compact, zero-padded bf16 A-matrix
//   PFB[g][m][k] (m = gender-compact slot, 256 rows, 224 cols)
// ---------------------------------------------------------------------------
__global__ void k_pf(float* __restrict__ W)
{
  const int bid = blockIdx.x;          // 0..511
  const int g = bid >> 8, m = bid & 255;
  const int k = threadIdx.x;
  if (k >= 224) return;
  const int* cnt = (const int*)(W + WS_CNT);
  const int* ord = (const int*)(W + WS_ORD);
  const int n_g = cnt[g];
  const int g0off = g ? cnt[0] : 0;
  unsigned short v = 0;
  if (m < n_g && k < KPD) {
    const int b = ord[g0off + m];
    v = f2bf(W[WS_PF + (size_t)b * KPD + k]);
  }
  ((unsigned short*)(W + WS_PFB))[((size_t)g * 256 + m) * 224 + k] = v;
}

// ---------------------------------------------------------------------------
// K3: per-batch: J from decomposition, kinematic chain, new_J out, A to ws
// ---------------------------------------------------------------------------
__launch_bounds__(128)
__global__ void k3_chain(float* __restrict__ out, float* __restrict__ W)
{
  const int b = blockIdx.x, tid = threadIdx.x;
  __shared__ float J[72];
  __shared__ float G[24][12];
  __shared__ float j0s[3];
  const int gi = ((const int*)(W + WS_GI))[b];
  if (tid < 72) {
    const int j = tid / 3, d = tid % 3;
    float v = W[WS_JT + (gi * 24 + j) * 3 + d];
    const float* bet = W + WS_BETA + b * 10;
#pragma unroll
    for (int k = 0; k < 10; k++)
      v += bet[k] * W[WS_JS + ((gi * 10 + k) * 24 + j) * 3 + d];
    J[tid] = v;
  }
  __syncthreads();
  const float* Rs = W + WS_RS + (size_t)b * 216;
  if (tid < 12) {
    const int row = tid / 4, col = tid % 4;
    G[0][tid] = (col < 3) ? Rs[row * 3 + col] : J[row];
  }
  __syncthreads();
  for (int i = 1; i < 24; i++) {
    const int p = PAR_c[i];
    if (tid < 12) {
      const int row = tid / 4, col = tid % 4;
      const float* Ri = Rs + i * 9;
      const float g0 = G[p][row * 4 + 0], g1 = G[p][row * 4 + 1], g2 = G[p][row * 4 + 2];
      float v;
      if (col < 3) {
        v = g0 * Ri[col] + g1 * Ri[3 + col] + g2 * Ri[6 + col];
      } else {
        const float t0 = J[i * 3 + 0] - J[p * 3 + 0];
        const float t1 = J[i * 3 + 1] - J[p * 3 + 1];
        const float t2 = J[i * 3 + 2] - J[p * 3 + 2];
        v = g0 * t0 + g1 * t1 + g2 * t2 + G[p][row * 4 + 3];
      }
      G[i][tid] = v;
    }
    __syncthreads();
  }
  if (tid < 3) {
    const float v = W[WS_RSH + b * 3 + tid] - J[tid];
    j0s[tid] = v;
    W[WS_J0S + b * 3 + tid] = v;
  }
  __syncthreads();
  if (tid < 72) {
    const int j = tid / 3, d = tid % 3;
    out[OFF_NEWJ + (size_t)b * 72 + tid] = G[j][d * 4 + 3] + j0s[d];
  }
  for (int e = tid; e < 288; e += 128) {
    const int j = e / 12, rc = e % 12, row = rc / 4, col = rc % 4;
    float v = G[j][rc];
    if (col == 3)
      v -= G[j][row * 4 + 0] * J[j * 3 + 0] + G[j][row * 4 + 1] * J[j * 3 + 1] + G[j][row * 4 + 2] * J[j * 3 + 2];
    W[WS_A + (size_t)b * 288 + e] = v;
  }
}

// ---------------------------------------------------------------------------
// K4a: MFMA GEMM — VP[b][n] = sum_k PFB[g][slot(b)][k] * PD[g][n][k]
//   n = r*3+d (20670 per gender), K = 207 (padded 224). PD streamed ONCE,
//   coalesced (per wave: 16 rows x 128B chunks). VP written into out-verts.
// ---------------------------------------------------------------------------
__launch_bounds__(256, 3)
__global__ void k4a_gemm(const float* __restrict__ pd, float* __restrict__ out,
                         const float* __restrict__ W)
{
  const int tid = threadIdx.x;
  const int wave = tid >> 6, lane = tid & 63;
  const int g = blockIdx.y;
  const int nb = blockIdx.x * 64 + wave * 16;       // this wave's 16-col subtile
  const int nfrac = lane & 15;
  const int kq = (lane >> 4) * 8;                   // k sub-offset within 32-chunk
  const int n = nb + nfrac;
  const bool nok = (n < RD3);
  const int nc = nok ? n : (RD3 - 1);
  const int* cnt = (const int*)(W + WS_CNT);
  const int* ord = (const int*)(W + WS_ORD);
  const int n_g = cnt[g];
  const int g0off = g ? cnt[0] : 0;

  // ---- B fragments: 7 k-chunks of PD row nc ----
  v8s bfr[7];
  const size_t rowbase = ((size_t)g * RD3 + nc) * KPD;
#pragma unroll
  for (int c = 0; c < 6; c++) {
    float f[8];
    __builtin_memcpy(f, pd + rowbase + c * 32 + kq, 32);  // rows are 4B-aligned only
    union { v8s v; unsigned short s[8]; } pk;
#pragma unroll
    for (int t = 0; t < 8; t++) pk.s[t] = f2bf(f[t]);
    bfr[c] = pk.v;
  }
  { // tail chunk c=6: k = 192 + kq + t, predicate k < 207 (OOB-safe, A is 0 there)
    union { v8s v; unsigned short s[8]; } pk;
#pragma unroll
    for (int t = 0; t < 8; t++) {
      const int k = 192 + kq + t;
      pk.s[t] = (k < KPD) ? f2bf(pd[rowbase + k]) : (unsigned short)0;
    }
    bfr[6] = pk.v;
  }

  const unsigned short* pfb = (const unsigned short*)(W + WS_PFB) + (size_t)g * 256 * 224;

  // ---- 16 M-tiles of 16 batches; one acc tile live at a time ----
#pragma unroll
  for (int mt = 0; mt < 16; mt++) {
    const unsigned short* ap = pfb + (size_t)(mt * 16 + nfrac) * 224 + kq;
    v4f acc = {0.f, 0.f, 0.f, 0.f};
#pragma unroll
    for (int c = 0; c < 7; c++) {
      const v8s af = *(const v8s*)(ap + c * 32);
      acc = __builtin_amdgcn_mfma_f32_16x16x32_bf16(af, bfr[c], acc, 0, 0, 0);
    }
    // C write: row m = mt*16 + (lane>>4)*4 + j, col = n
    const int mrow = mt * 16 + (lane >> 4) * 4;
#pragma unroll
    for (int j = 0; j < 4; j++) {
      const int m = mrow + j;
      if (m < n_g && nok) {
        const int b = ord[g0off + m];
        out[OFF_VERTS + (size_t)b * RD3 + n] = acc[j];
      }
    }
  }
}

// ---------------------------------------------------------------------------
// K4b: v_shaped + LBS skinning. Block = 256 verts x BT=16 batches (one gender).
// Reads VP from out-verts region, overwrites with final verts.
// ---------------------------------------------------------------------------
__launch_bounds__(256, 3)
__global__ void k4b_verts(const float* __restrict__ vtemp, const float* __restrict__ sdirs,
                          const float* __restrict__ wts, float* __restrict__ out,
                          const float* __restrict__ W)
{
  __shared__ __align__(16) float s_A[BT][288];
  __shared__ float s_bet[BT][10];
  __shared__ float s_j0s[BT][3];
  __shared__ int s_bidx[BT];

  const int tid = threadIdx.x;
  const int* cnt = (const int*)(W + WS_CNT);
  const int* ord = (const int*)(W + WS_ORD);
  const int B0 = cnt[0], B1 = cnt[1];
  const int T0 = (B0 + BT - 1) / BT, T1 = (B1 + BT - 1) / BT;
  const int bt = blockIdx.y;
  if (bt >= T0 + T1) return;   // uniform exit
  int g, start, n;
  if (bt < T0) { g = 0; start = bt * BT; n = B0 - start; }
  else { g = 1; start = B0 + (bt - T0) * BT; n = NB - start; }
  if (n > BT) n = BT;

  if (tid < BT) s_bidx[tid] = ord[start + (tid < n ? tid : 0)];
  for (int e = tid; e < BT * 288; e += 256) {
    const int i = e / 288, rem = e - i * 288;
    const int b = ord[start + (i < n ? i : 0)];
    s_A[i][rem] = W[WS_A + (size_t)b * 288 + rem];
  }
  for (int e = tid; e < BT * 10; e += 256) {
    const int i = e / 10, k = e - i * 10;
    const int b = ord[start + (i < n ? i : 0)];
    s_bet[i][k] = W[WS_BETA + b * 10 + k];
  }
  if (tid < BT * 3) {
    const int i = tid / 3, d = tid - i * 3;
    const int b = ord[start + (i < n ? i : 0)];
    s_j0s[i][d] = W[WS_J0S + b * 3 + d];
  }
  __syncthreads();

  const int r = blockIdx.x * 256 + tid;
  if (r >= NR) return;

  const float* vt3 = vtemp + ((size_t)g * NR + r) * 3;
  const float vt0 = vt3[0], vt1 = vt3[1], vt2 = vt3[2];
  float sdr[10][3];
#pragma unroll
  for (int k = 0; k < 10; k++) {
    const float* s = sdirs + ((size_t)g * 10 * NR + (size_t)k * NR + r) * 3;
    sdr[k][0] = s[0]; sdr[k][1] = s[1]; sdr[k][2] = s[2];
  }
  float w[24];
  const float* wr = wts + ((size_t)g * NR + r) * 24;
#pragma unroll
  for (int j = 0; j < 24; j += 4) {
    float4 wv; __builtin_memcpy(&wv, wr + j, 16);
    w[j] = wv.x; w[j + 1] = wv.y; w[j + 2] = wv.z; w[j + 3] = wv.w;
  }

#pragma unroll
  for (int i = 0; i < BT; i++) {
    const int b = s_bidx[i];
    float* vp = out + OFF_VERTS + ((size_t)b * NR + r) * 3;
    // v_posed = VP (pose GEMM result) + v_template + betas·shapedirs
    float vx = vp[0] + vt0, vy = vp[1] + vt1, vz = vp[2] + vt2;
#pragma unroll
    for (int k = 0; k < 10; k++) {
      const float bk = s_bet[i][k];
      vx += bk * sdr[k][0]; vy += bk * sdr[k][1]; vz += bk * sdr[k][2];
    }
    float T[12];
#pragma unroll
    for (int e = 0; e < 12; e++) T[e] = 0.f;
#pragma unroll
    for (int j = 0; j < 24; j++) {
      const float wj = w[j];
      const float4 a0 = *(const float4*)&s_A[i][j * 12];
      const float4 a1 = *(const float4*)&s_A[i][j * 12 + 4];
      const float4 a2 = *(const float4*)&s_A[i][j * 12 + 8];
      T[0] += wj * a0.x; T[1] += wj * a0.y; T[2]  += wj * a0.z; T[3]  += wj * a0.w;
      T[4] += wj * a1.x; T[5] += wj * a1.y; T[6]  += wj * a1.z; T[7]  += wj * a1.w;
      T[8] += wj * a2.x; T[9] += wj * a2.y; T[10] += wj * a2.z; T[11] += wj * a2.w;
    }
    if (i < n) {
      const float o0 = T[0] * vx + T[1] * vy + T[2]  * vz + T[3]  + s_j0s[i][0];
      const float o1 = T[4] * vx + T[5] * vy + T[6]  * vz + T[7]  + s_j0s[i][1];
      const float o2 = T[8] * vx + T[9] * vy + T[10] * vz + T[11] + s_j0s[i][2];
      vp[0] = o0; vp[1] = o1; vp[2] = o2;
    }
  }
}

// ---------------------------------------------------------------------------
// K5: gather verts_red and verts_offset
// ---------------------------------------------------------------------------
__global__ void k5_gather(float* __restrict__ out)
{
  const int idx = blockIdx.x * 256 + threadIdx.x;
  if (idx >= NB * 10 * 3) return;
  const int b = idx / 30, rem = idx % 30, i = rem / 3, d = rem % 3;
  const float v = out[OFF_VERTS + ((size_t)b * NR + VL_c[i]) * 3 + d];
  out[OFF_VRED + idx] = v;
  out[OFF_VOFF + idx] = v - out[OFF_NEWJ + (size_t)b * 72 + SY_c[i] * 3 + d];
}

// ---------------------------------------------------------------------------
extern "C" void kernel_launch(void* const* d_in, const int* in_sizes, int n_in,
                              void* d_out, int out_size, void* d_ws, size_t ws_size,
                              hipStream_t stream)
{
  const float* x   = (const float*)d_in[0];
  const float* gen = (const float*)d_in[1];
  const float* vt  = (const float*)d_in[2];
  const float* sd  = (const float*)d_in[3];
  const float* jr  = (const float*)d_in[4];
  const float* pd  = (const float*)d_in[5];
  const float* wt  = (const float*)d_in[6];
  float* out = (float*)d_out;
  float* W   = (float*)d_ws;

  k1_pose<<<NB, 64, 0, stream>>>(x, gen, out, W);
  k2_jreg<<<48, 512, 0, stream>>>(vt, sd, jr, W);
  k_order<<<1, 256, 0, stream>>>(W);
  k_pf<<<512, 256, 0, stream>>>(W);
  k3_chain<<<NB, 128, 0, stream>>>(out, W);
  k4a_gemm<<<dim3((RD3 + 63) / 64, 2), 256, 0, stream>>>(pd, out, W);
  k4b_verts<<<dim3(27, 17), 256, 0, stream>>>(vt, sd, wt, out, W);
  k5_gather<<<30, 256, 0, stream>>>(out);
}

// Round 4
// 118.202 us; speedup vs baseline: 7.1639x; 1.2464x over previous
//
#include <hip/hip_runtime.h>
#include <hip/hip_bf16.h>

// ---------------------------------------------------------------------------
// MeshEstimator (SMPL-like) forward.  B=256, R=6890, 24 joints, 207 pose dims.
// R3 -> R4: k4b occupancy fix (BT=8, 128-thr blocks, 1782 blocks, o-form LBS);
// k2 split into 384 blocks w/ partials in out-verts scratch (reduced in k3);
// k3 level-parallel kinematic chain (8 steps), 64-thr blocks.
// ---------------------------------------------------------------------------

#define NB 256
#define NR 6890
#define NJ 24
#define BT 8        // batches per k4b block
#define RD3 (NR*3)  // 20670
#define KPD 207
#define K2C 8       // k2 r-chunks
#define K2R 862     // rows per chunk (862*8 >= 6890)

// ---- output offsets (floats) ----
#define OFF_BETAS 0
#define OFF_POSE  2560
#define OFF_RSH   20992
#define OFF_RA    21760
#define OFF_VERTS 23296
#define OFF_VRED  5314816
#define OFF_NEWJ  5322496
#define OFF_VOFF  5340928

// ---- workspace offsets (floats) ----
#define WS_RS    0         // Rs: 256*24*9 = 55296
#define WS_PF    55296     // pose_feat: 256*207 = 52992
#define WS_BETA  108288    // 2560
#define WS_RSH   110848    // 768
#define WS_GI    111616    // 256 ints
#define WS_A     113456    // 256*24*12 = 73728
#define WS_J0S   187184    // 768
#define WS_ORD   187952    // 256 ints
#define WS_CNT   188208    // 2 ints
#define WS_PFB   188224    // bf16 A-matrix: 2*256*224 ushort = 57344 floats

typedef short v8s __attribute__((ext_vector_type(8)));
typedef float v4f __attribute__((ext_vector_type(4)));

__constant__ int PAR_c[24] = {0,0,0,0,1,2,3,4,5,6,7,8,9,9,9,12,13,14,16,17,18,19,20,21};
__constant__ int VL_c[10]  = {1325,336,1032,4515,1374,4848,1739,5209,1960,5423};
__constant__ int SY_c[10]  = {3,15,4,5,7,8,18,19,20,21};
// kinematic-tree levels (joints of equal depth computed in parallel)
__constant__ int LVL_j[23]  = {1,2,3, 4,5,6, 7,8,9, 10,11,12,13,14, 15,16,17, 18,19, 20,21, 22,23};
__constant__ int LVL_off[9] = {0,3,6,9,14,17,19,21,23};

__constant__ float BLO[72] = {
  -0.5933865286111969f, -6.283185307179586f, -1.215762200416361f,
  -1.5793940868065197f, -0.5881754611f, -0.5323249722f,
  -1.5793940868065197f, -0.5689768556f, -0.6736965222f,
  -1.0471975511965976f, -0.08726646259971647f, -0.08726646259971647f,
  -0.02268926111f, -0.01f, -0.01f,
  -0.02268926111f, -0.01f, -0.01f,
  -1.0471975511965976f, -0.08726646259971647f, -0.08726646259971647f,
  -0.5235987755982988f, -0.5235987755982988f, -0.5235987755982988f,
  -0.5235987755982988f, -0.5235987755982988f, -0.5235987755982988f,
  -1.0471975511965976f, -0.08726646259971647f, -0.08726646259971647f,
  -0.01f, -0.01f, -0.01f, -0.01f, -0.01f, -0.01f,
  -1.0471975511965976f, -0.08726646259971647f, -0.08726646259971647f,
  (float)(-1.551596394/3.0), (float)(-2.455676183/3.0), (float)(-1.570795/3.0),
  (float)(-1.551596394/3.0), (float)(-0.7627082389/3.0), (float)(-2.188641033/3.0),
  -1.0471975511965976f, -0.08726646259971647f, -0.08726646259971647f,
  (float)(-1.551596394*2.0/3.0), (float)(-2.455676183*2.0/3.0), (float)(-1.570795*2.0/3.0),
  (float)(-1.551596394*2.0/3.0), (float)(-0.7627082389*2.0/3.0), (float)(-2.188641033*2.0/3.0),
  -0.01f, -2.570867817f, -0.01f, -0.01f, -0.04799651389f, -0.01f,
  -0.5235987755982988f, -0.5235987755982988f, -0.5235987755982988f,
  -0.5235987755982988f, -0.5235987755982988f, -0.5235987755982988f,
  -0.01f, -0.01f, -0.01f, -0.01f, -0.01f, -0.01f
};
__constant__ float BHI[72] = {
  0.5933865286111969f, 6.283185307179586f, 1.215762200416361f,
  0.3097956806f, 0.5689768556f, 0.6736965222f,
  0.3097956806f, 0.5881754611f, 0.5323249722f,
  1.0471975511965976f, 0.08726646259971647f, 0.08726646259971647f,
  2.441713561f, 0.01f, 0.01f,
  2.441713561f, 0.01f, 0.01f,
  1.0471975511965976f, 0.08726646259971647f, 0.08726646259971647f,
  0.5235987755982988f, 0.5235987755982988f, 0.5235987755982988f,
  0.5235987755982988f, 0.5235987755982988f, 0.5235987755982988f,
  1.0471975511965976f, 0.08726646259971647f, 0.08726646259971647f,
  0.01f, 0.01f, 0.01f, 0.01f, 0.01f, 0.01f,
  1.0471975511965976f, 0.08726646259971647f, 0.08726646259971647f,
  (float)(2.206094311/3.0), (float)(0.7627082389/3.0), (float)(2.188641033/3.0),
  (float)(2.206094311/3.0), (float)(2.455676183/3.0), (float)(1.570795/3.0),
  1.0471975511965976f, 0.08726646259971647f, 0.08726646259971647f,
  (float)(2.206094311*2.0/3.0), (float)(0.7627082389*2.0/3.0), (float)(2.188641033*2.0/3.0),
  (float)(2.206094311*2.0/3.0), (float)(2.455676183*2.0/3.0), (float)(1.570795*2.0/3.0),
  0.01f, 0.04799651389f, 0.01f, 0.01f, 2.570867817f, 0.01f,
  0.5235987755982988f, 0.5235987755982988f, 0.5235987755982988f,
  0.5235987755982988f, 0.5235987755982988f, 0.5235987755982988f,
  0.01f, 0.01f, 0.01f, 0.01f, 0.01f, 0.01f
};

__device__ __forceinline__ unsigned short f2bf(float f) {
  union { float f; unsigned u; } c; c.f = f;
  const unsigned u = c.u + 0x7FFFu + ((c.u >> 16) & 1u);   // RNE
  return (unsigned short)(u >> 16);
}

// ---------------------------------------------------------------------------
// K1: per-batch pose clamp, Rodrigues, betas, root outputs, gender index
// ---------------------------------------------------------------------------
__global__ void k1_pose(const float* __restrict__ x, const float* __restrict__ gen,
                        float* __restrict__ out, float* __restrict__ W)
{
  const int b = blockIdx.x, tid = threadIdx.x;
  const float* xb = x + b * 88;
  if (tid < 24) {
    const int j = tid;
    float t[3];
    if (j == 0) {
      t[0] = atan2f(xb[16], xb[13]);
      t[1] = atan2f(xb[17], xb[14]);
      t[2] = atan2f(xb[18], xb[15]);
    } else {
      t[0] = xb[19 + (j - 1) * 3 + 0];
      t[1] = xb[19 + (j - 1) * 3 + 1];
      t[2] = xb[19 + (j - 1) * 3 + 2];
    }
#pragma unroll
    for (int c = 0; c < 3; c++) {
      const int pi = j * 3 + c;
      const float lo = 2.f * BLO[pi], hi = 2.f * BHI[pi];
      const float mean = 0.5f * (lo + hi);
      const float scale = 2.f / fabsf(lo - hi);
      const float v = tanhf((t[c] - mean) * scale) / scale + mean;
      t[c] = v;
      out[OFF_POSE + b * 72 + pi] = v;
    }
    const float a0 = t[0] + 1e-8f, a1 = t[1] + 1e-8f, a2 = t[2] + 1e-8f;
    const float ang = sqrtf(a0 * a0 + a1 * a1 + a2 * a2);
    const float half = 0.5f * ang;
    const float sh = sinf(half), ch = cosf(half);
    const float inv = sh / ang;
    float qw = ch, qx = t[0] * inv, qy = t[1] * inv, qz = t[2] * inv;
    const float nn = sqrtf(qw * qw + qx * qx + qy * qy + qz * qz);
    qw /= nn; qx /= nn; qy /= nn; qz /= nn;
    float R[9];
    R[0] = 1.f - 2.f * (qy * qy + qz * qz); R[1] = 2.f * (qx * qy - qw * qz); R[2] = 2.f * (qx * qz + qw * qy);
    R[3] = 2.f * (qx * qy + qw * qz); R[4] = 1.f - 2.f * (qx * qx + qz * qz); R[5] = 2.f * (qy * qz - qw * qx);
    R[6] = 2.f * (qx * qz - qw * qy); R[7] = 2.f * (qy * qz + qw * qx); R[8] = 1.f - 2.f * (qx * qx + qy * qy);
    float* rsw = W + WS_RS + (size_t)(b * 24 + j) * 9;
#pragma unroll
    for (int e = 0; e < 9; e++) rsw[e] = R[e];
    if (j >= 1) {
      float* pfw = W + WS_PF + (size_t)b * 207 + (j - 1) * 9;
#pragma unroll
      for (int e = 0; e < 9; e++)
        pfw[e] = R[e] - ((e == 0 || e == 4 || e == 8) ? 1.f : 0.f);
    }
  } else if (tid < 34) {
    const int k = tid - 24;
    const float v = tanhf(xb[k] / 3.0f) * 3.0f;
    out[OFF_BETAS + b * 10 + k] = v;
    W[WS_BETA + b * 10 + k] = v;
  } else if (tid == 34) {
    const float r0 = xb[10] + (0.6f - 0.286f);
    const float r1 = xb[11] + (1.2f - 0.286f);
    const float r2 = xb[12] + 0.1f;
    out[OFF_RSH + b * 3 + 0] = r0; out[OFF_RSH + b * 3 + 1] = r1; out[OFF_RSH + b * 3 + 2] = r2;
    W[WS_RSH + b * 3 + 0] = r0; W[WS_RSH + b * 3 + 1] = r1; W[WS_RSH + b * 3 + 2] = r2;
#pragma unroll
    for (int k2 = 0; k2 < 6; k2++) out[OFF_RA + b * 6 + k2] = xb[13 + k2];
  } else if (tid == 35) {
    ((int*)(W + WS_GI))[b] = (gen[b * 2 + 1] > gen[b * 2 + 0]) ? 1 : 0;
  }
}

// ---------------------------------------------------------------------------
// K2: joint-regressor partials over r-chunks. Grid = 2*24*K2C = 384 blocks.
// Partial[g,j,c][33] written into out-verts region (scratch until k4a).
// ---------------------------------------------------------------------------
__global__ void k2_jreg(const float* __restrict__ vtemp, const float* __restrict__ sdirs,
                        const float* __restrict__ jreg, float* __restrict__ out)
{
  const int bid = blockIdx.x;
  const int c = bid % K2C, j = (bid / K2C) % 24, g = bid / (K2C * 24);
  const int r0 = c * K2R;
  int r1 = r0 + K2R; if (r1 > NR) r1 = NR;
  const float* vtg = vtemp + (size_t)g * NR * 3;
  const float* sdg = sdirs + (size_t)g * 10 * NR * 3;
  const float* jrg = jreg + (size_t)g * NR * 24;
  float acc[33];
#pragma unroll
  for (int e = 0; e < 33; e++) acc[e] = 0.f;
  for (int r = r0 + threadIdx.x; r < r1; r += 256) {
    const float w = jrg[r * 24 + j];
    acc[0] += vtg[r * 3 + 0] * w;
    acc[1] += vtg[r * 3 + 1] * w;
    acc[2] += vtg[r * 3 + 2] * w;
#pragma unroll
    for (int k = 0; k < 10; k++) {
      const float* s = sdg + ((size_t)k * NR + r) * 3;
      acc[3 + k * 3 + 0] += s[0] * w;
      acc[3 + k * 3 + 1] += s[1] * w;
      acc[3 + k * 3 + 2] += s[2] * w;
    }
  }
  __shared__ float red[4][33];
  const int lane = threadIdx.x & 63, wv = threadIdx.x >> 6;
#pragma unroll
  for (int e = 0; e < 33; e++) {
    float v = acc[e];
    v += __shfl_down(v, 32); v += __shfl_down(v, 16); v += __shfl_down(v, 8);
    v += __shfl_down(v, 4);  v += __shfl_down(v, 2);  v += __shfl_down(v, 1);
    if (lane == 0) red[wv][e] = v;
  }
  __syncthreads();
  if (threadIdx.x < 33) {
    const int e = threadIdx.x;
    out[OFF_VERTS + (size_t)(((g * 24 + j) * K2C + c) * 33 + e)] =
        red[0][e] + red[1][e] + red[2][e] + red[3][e];
  }
}

// ---------------------------------------------------------------------------
// K_order: ballot-based stable compaction of batches by gender
// ---------------------------------------------------------------------------
__global__ void k_order(float* __restrict__ W)
{
  const int tid = threadIdx.x;              // == batch index
  const int* gi = (const int*)(W + WS_GI);
  int* ord = (int*)(W + WS_ORD);
  int* cnt = (int*)(W + WS_CNT);
  const int g = gi[tid];
  const int lane = tid & 63, wv = tid >> 6;
  const unsigned long long b0 = __ballot(g == 0);
  __shared__ int c0[4];
  if (lane == 0) c0[wv] = __popcll(b0);
  __syncthreads();
  const int t0 = c0[0] + c0[1] + c0[2] + c0[3];
  int off0 = 0, off1 = t0;
  for (int w = 0; w < wv; w++) { off0 += c0[w]; off1 += 64 - c0[w]; }
  const unsigned long long ltm = (1ull << lane) - 1ull;
  const int r0 = __popcll(b0 & ltm);
  const int r1 = lane - r0;
  if (g == 0) ord[off0 + r0] = tid;
  else        ord[off1 + r1] = tid;
  if (tid == 0) { cnt[0] = t0; cnt[1] = NB - t0; }
}

// ---------------------------------------------------------------------------
// K_pf: pack pose features into compact, zero-padded bf16 A-matrix
// ---------------------------------------------------------------------------
__global__ void k_pf(float* __restrict__ W)
{
  const int bid = blockIdx.x;          // 0..511
  const int g = bid >> 8, m = bid & 255;
  const int k = threadIdx.x;
  if (k >= 224) return;
  const int* cnt = (const int*)(W + WS_CNT);
  const int* ord = (const int*)(W + WS_ORD);
  const int n_g = cnt[g];
  const int g0off = g ? cnt[0] : 0;
  unsigned short v = 0;
  if (m < n_g && k < KPD) {
    const int b = ord[g0off + m];
    v = f2bf(W[WS_PF + (size_t)b * KPD + k]);
  }
  ((unsigned short*)(W + WS_PFB))[((size_t)g * 256 + m) * 224 + k] = v;
}

// ---------------------------------------------------------------------------
// K3: per-batch: J from k2 partials, level-parallel kinematic chain (8 steps),
// new_J out, A to ws. 64 threads/block.
// ---------------------------------------------------------------------------
__launch_bounds__(64)
__global__ void k3_chain(float* __restrict__ out, float* __restrict__ W)
{
  const int b = blockIdx.x, tid = threadIdx.x;
  __shared__ float J[72];
  __shared__ float G[24][12];
  __shared__ float j0s[3];
  const int gi = ((const int*)(W + WS_GI))[b];
  float bb[10];
#pragma unroll
  for (int k = 0; k < 10; k++) bb[k] = W[WS_BETA + b * 10 + k];

  for (int e2 = tid; e2 < 72; e2 += 64) {
    const int j = e2 / 3, d = e2 % 3;
    float v = 0.f;
#pragma unroll
    for (int c = 0; c < K2C; c++) {
      const float* P = out + OFF_VERTS + (size_t)(((gi * 24 + j) * K2C + c) * 33);
      float s = P[d];
#pragma unroll
      for (int k = 0; k < 10; k++) s += bb[k] * P[3 + k * 3 + d];
      v += s;
    }
    J[e2] = v;
  }
  __syncthreads();
  const float* Rs = W + WS_RS + (size_t)b * 216;
  if (tid < 12) {
    const int row = tid / 4, col = tid % 4;
    G[0][tid] = (col < 3) ? Rs[row * 3 + col] : J[row];
  }
  __syncthreads();
#pragma unroll
  for (int L = 0; L < 8; L++) {
    const int base = LVL_off[L];
    const int cntL = LVL_off[L + 1] - base;
    const int slot = tid / 12, e = tid - slot * 12;
    if (slot < cntL) {
      const int i = LVL_j[base + slot];
      const int p = PAR_c[i];
      const int row = e / 4, col = e - row * 4;
      const float* Ri = Rs + i * 9;
      const float g0 = G[p][row * 4 + 0], g1 = G[p][row * 4 + 1], g2 = G[p][row * 4 + 2];
      float v;
      if (col < 3) {
        v = g0 * Ri[col] + g1 * Ri[3 + col] + g2 * Ri[6 + col];
      } else {
        const float t0 = J[i * 3 + 0] - J[p * 3 + 0];
        const float t1 = J[i * 3 + 1] - J[p * 3 + 1];
        const float t2 = J[i * 3 + 2] - J[p * 3 + 2];
        v = g0 * t0 + g1 * t1 + g2 * t2 + G[p][row * 4 + 3];
      }
      G[i][e] = v;
    }
    __syncthreads();
  }
  if (tid < 3) {
    const float v = W[WS_RSH + b * 3 + tid] - J[tid];
    j0s[tid] = v;
    W[WS_J0S + b * 3 + tid] = v;
  }
  __syncthreads();
  for (int e2 = tid; e2 < 72; e2 += 64) {
    const int j = e2 / 3, d = e2 % 3;
    out[OFF_NEWJ + (size_t)b * 72 + e2] = G[j][d * 4 + 3] + j0s[d];
  }
  for (int e = tid; e < 288; e += 64) {
    const int j = e / 12, rc = e - j * 12, row = rc / 4, col = rc - row * 4;
    float v = G[j][rc];
    if (col == 3)
      v -= G[j][row * 4 + 0] * J[j * 3 + 0] + G[j][row * 4 + 1] * J[j * 3 + 1] + G[j][row * 4 + 2] * J[j * 3 + 2];
    W[WS_A + (size_t)b * 288 + e] = v;
  }
}

// ---------------------------------------------------------------------------
// K4a: MFMA GEMM — VP[b][n] = sum_k PFB[g][slot(b)][k] * PD[g][n][k]
// ---------------------------------------------------------------------------
__launch_bounds__(256, 3)
__global__ void k4a_gemm(const float* __restrict__ pd, float* __restrict__ out,
                         const float* __restrict__ W)
{
  const int tid = threadIdx.x;
  const int wave = tid >> 6, lane = tid & 63;
  const int g = blockIdx.y;
  const int nb = blockIdx.x * 64 + wave * 16;       // this wave's 16-col subtile
  const int nfrac = lane & 15;
  const int kq = (lane >> 4) * 8;                   // k sub-offset within 32-chunk
  const int n = nb + nfrac;
  const bool nok = (n < RD3);
  const int nc = nok ? n : (RD3 - 1);
  const int* cnt = (const int*)(W + WS_CNT);
  const int* ord = (const int*)(W + WS_ORD);
  const int n_g = cnt[g];
  const int g0off = g ? cnt[0] : 0;

  // ---- B fragments: 7 k-chunks of PD row nc ----
  v8s bfr[7];
  const size_t rowbase = ((size_t)g * RD3 + nc) * KPD;
#pragma unroll
  for (int c = 0; c < 6; c++) {
    float f[8];
    __builtin_memcpy(f, pd + rowbase + c * 32 + kq, 32);  // rows are 4B-aligned only
    union { v8s v; unsigned short s[8]; } pk;
#pragma unroll
    for (int t = 0; t < 8; t++) pk.s[t] = f2bf(f[t]);
    bfr[c] = pk.v;
  }
  { // tail chunk c=6: k = 192 + kq + t, predicate k < 207
    union { v8s v; unsigned short s[8]; } pk;
#pragma unroll
    for (int t = 0; t < 8; t++) {
      const int k = 192 + kq + t;
      pk.s[t] = (k < KPD) ? f2bf(pd[rowbase + k]) : (unsigned short)0;
    }
    bfr[6] = pk.v;
  }

  const unsigned short* pfb = (const unsigned short*)(W + WS_PFB) + (size_t)g * 256 * 224;

#pragma unroll
  for (int mt = 0; mt < 16; mt++) {
    const unsigned short* ap = pfb + (size_t)(mt * 16 + nfrac) * 224 + kq;
    v4f acc = {0.f, 0.f, 0.f, 0.f};
#pragma unroll
    for (int c = 0; c < 7; c++) {
      const v8s af = *(const v8s*)(ap + c * 32);
      acc = __builtin_amdgcn_mfma_f32_16x16x32_bf16(af, bfr[c], acc, 0, 0, 0);
    }
    const int mrow = mt * 16 + (lane >> 4) * 4;
#pragma unroll
    for (int j = 0; j < 4; j++) {
      const int m = mrow + j;
      if (m < n_g && nok) {
        const int b = ord[g0off + m];
        out[OFF_VERTS + (size_t)b * RD3 + n] = acc[j];
      }
    }
  }
}

// ---------------------------------------------------------------------------
// K4b: v_shaped + LBS skinning. Block = 128 verts x BT=8 batches (one gender).
// Grid 54x33 = 1782 blocks. o-form LBS: o += w_j * (A_j . [v,1]).
// ---------------------------------------------------------------------------
__launch_bounds__(128, 4)
__global__ void k4b_verts(const float* __restrict__ vtemp, const float* __restrict__ sdirs,
                          const float* __restrict__ wts, float* __restrict__ out,
                          const float* __restrict__ W)
{
  __shared__ __align__(16) float s_A[BT][288];
  __shared__ float s_bet[BT][10];
  __shared__ float s_j0s[BT][3];
  __shared__ int s_bidx[BT];

  const int tid = threadIdx.x;
  const int* cnt = (const int*)(W + WS_CNT);
  const int* ord = (const int*)(W + WS_ORD);
  const int B0 = cnt[0], B1 = cnt[1];
  const int T0 = (B0 + BT - 1) / BT, T1 = (B1 + BT - 1) / BT;
  const int bt = blockIdx.y;
  if (bt >= T0 + T1) return;   // uniform exit (before any barrier)
  int g, start, n;
  if (bt < T0) { g = 0; start = bt * BT; n = B0 - start; }
  else { g = 1; start = B0 + (bt - T0) * BT; n = NB - start; }
  if (n > BT) n = BT;

  if (tid < BT) s_bidx[tid] = ord[start + (tid < n ? tid : 0)];
  for (int e = tid; e < BT * 288; e += 128) {
    const int i = e / 288, rem = e - i * 288;
    const int b = ord[start + (i < n ? i : 0)];
    s_A[i][rem] = W[WS_A + (size_t)b * 288 + rem];
  }
  for (int e = tid; e < BT * 10; e += 128) {
    const int i = e / 10, k = e - i * 10;
    const int b = ord[start + (i < n ? i : 0)];
    s_bet[i][k] = W[WS_BETA + b * 10 + k];
  }
  if (tid < BT * 3) {
    const int i = tid / 3, d = tid - i * 3;
    const int b = ord[start + (i < n ? i : 0)];
    s_j0s[i][d] = W[WS_J0S + b * 3 + d];
  }
  __syncthreads();

  const int r = blockIdx.x * 128 + tid;
  if (r >= NR) return;

  const float* vt3 = vtemp + ((size_t)g * NR + r) * 3;
  const float vt0 = vt3[0], vt1 = vt3[1], vt2 = vt3[2];
  float sdr[10][3];
#pragma unroll
  for (int k = 0; k < 10; k++) {
    const float* s = sdirs + ((size_t)g * 10 * NR + (size_t)k * NR + r) * 3;
    sdr[k][0] = s[0]; sdr[k][1] = s[1]; sdr[k][2] = s[2];
  }
  float w[24];
  const float* wr = wts + ((size_t)g * NR + r) * 24;
#pragma unroll
  for (int j = 0; j < 24; j += 4) {
    float4 wv; __builtin_memcpy(&wv, wr + j, 16);
    w[j] = wv.x; w[j + 1] = wv.y; w[j + 2] = wv.z; w[j + 3] = wv.w;
  }

#pragma unroll
  for (int i = 0; i < BT; i++) {
    const int b = s_bidx[i];
    float* vp = out + OFF_VERTS + ((size_t)b * NR + r) * 3;
    float vx = vp[0] + vt0, vy = vp[1] + vt1, vz = vp[2] + vt2;
#pragma unroll
    for (int k = 0; k < 10; k++) {
      const float bk = s_bet[i][k];
      vx += bk * sdr[k][0]; vy += bk * sdr[k][1]; vz += bk * sdr[k][2];
    }
    float o0 = s_j0s[i][0], o1 = s_j0s[i][1], o2 = s_j0s[i][2];
#pragma unroll
    for (int j = 0; j < 24; j++) {
      const float wj = w[j];
      const float4 a0 = *(const float4*)&s_A[i][j * 12];
      const float4 a1 = *(const float4*)&s_A[i][j * 12 + 4];
      const float4 a2 = *(const float4*)&s_A[i][j * 12 + 8];
      const float r0 = fmaf(a0.x, vx, fmaf(a0.y, vy, fmaf(a0.z, vz, a0.w)));
      const float r1 = fmaf(a1.x, vx, fmaf(a1.y, vy, fmaf(a1.z, vz, a1.w)));
      const float r2 = fmaf(a2.x, vx, fmaf(a2.y, vy, fmaf(a2.z, vz, a2.w)));
      o0 = fmaf(wj, r0, o0); o1 = fmaf(wj, r1, o1); o2 = fmaf(wj, r2, o2);
    }
    if (i < n) { vp[0] = o0; vp[1] = o1; vp[2] = o2; }
  }
}

// ---------------------------------------------------------------------------
// K5: gather verts_red and verts_offset
// ---------------------------------------------------------------------------
__global__ void k5_gather(float* __restrict__ out)
{
  const int idx = blockIdx.x * 256 + threadIdx.x;
  if (idx >= NB * 10 * 3) return;
  const int b = idx / 30, rem = idx % 30, i = rem / 3, d = rem % 3;
  const float v = out[OFF_VERTS + ((size_t)b * NR + VL_c[i]) * 3 + d];
  out[OFF_VRED + idx] = v;
  out[OFF_VOFF + idx] = v - out[OFF_NEWJ + (size_t)b * 72 + SY_c[i] * 3 + d];
}

// ---------------------------------------------------------------------------
extern "C" void kernel_launch(void* const* d_in, const int* in_sizes, int n_in,
                              void* d_out, int out_size, void* d_ws, size_t ws_size,
                              hipStream_t stream)
{
  const float* x   = (const float*)d_in[0];
  const float* gen = (const float*)d_in[1];
  const float* vt  = (const float*)d_in[2];
  const float* sd  = (const float*)d_in[3];
  const float* jr  = (const float*)d_in[4];
  const float* pd  = (const float*)d_in[5];
  const float* wt  = (const float*)d_in[6];
  float* out = (float*)d_out;
  float* W   = (float*)d_ws;

  k1_pose<<<NB, 64, 0, stream>>>(x, gen, out, W);
  k2_jreg<<<2 * 24 * K2C, 256, 0, stream>>>(vt, sd, jr, out);  // partials -> out-verts scratch
  k_order<<<1, 256, 0, stream>>>(W);
  k_pf<<<512, 256, 0, stream>>>(W);
  k3_chain<<<NB, 64, 0, stream>>>(out, W);                     // consumes partials
  k4a_gemm<<<dim3((RD3 + 63) / 64, 2), 256, 0, stream>>>(pd, out, W);  // overwrites scratch
  k4b_verts<<<dim3(54, 33), 128, 0, stream>>>(vt, sd, wt, out, W);
  k5_gather<<<30, 256, 0, stream>>>(out);
}